// Round 1
// baseline (215.706 us; speedup 1.0000x reference)
//
#include <hip/hip_runtime.h>

#define S_LEN 4096
#define HID   512
#define HD    128
#define WIN   512
#define LOG2_GAMMA (-0.0458036933f)   // log2(0.96875)

typedef short bf16x8 __attribute__((ext_vector_type(8)));
typedef float f32x4  __attribute__((ext_vector_type(4)));
typedef unsigned short u16;

static __device__ __forceinline__ u16 f2bf(float f) {
    union { float f; unsigned u; } v; v.f = f;
    unsigned r = (v.u + 0x7fffu + ((v.u >> 16) & 1u)) >> 16;  // RNE
    return (u16)r;
}

// ---------------- xpos tables: tab[n*64+i] = (cos*scale, sin*scale) ----------------
__global__ __launch_bounds__(256) void xpos_table_kernel(float2* __restrict__ tabQ,
                                                         float2* __restrict__ tabK) {
    int idx = blockIdx.x * 256 + threadIdx.x;      // 4096*64 items
    int n = idx >> 6, i = idx & 63;
    float base  = (2.0f * i + 51.2f) * (1.0f / 179.2f);       // (2i+0.4d)/(1.4d), d=128
    float power = (float)n * (1.0f / 512.0f);
    float scale = exp2f(power * log2f(base));
    float inv_freq = exp2f(-(float)i * (13.287712379549449f / 64.0f)); // 10000^(-i/64)
    float theta = (float)n * inv_freq;
    float s, c;
    sincosf(theta, &s, &c);
    tabQ[idx] = make_float2(c * scale, s * scale);
    float is = 1.0f / scale;
    tabK[idx] = make_float2(c * is, s * is);
}

// ---------------- weight transpose -> bf16, Wt[w][col][k] ----------------
__global__ __launch_bounds__(256) void wt_kernel(const float* __restrict__ WQ,
                                                 const float* __restrict__ WK,
                                                 const float* __restrict__ WV,
                                                 u16* __restrict__ Wt) {
    int idx = blockIdx.x * 256 + threadIdx.x;      // 3*128*512
    int w = idx >> 16;
    int rem = idx & 65535;
    int c = rem >> 9, k = rem & 511;
    const float* src = (w == 0) ? WQ : (w == 1) ? WK : WV;
    Wt[idx] = f2bf(src[k * HD + c]);
}

// ---------------- projections: 64-token tile, MFMA 16x16x32 bf16 ----------------
// grid.y: 0 = Q (X, xpos up), 1 = K (Mem, xpos down), 2 = V (Mem, transpose store)
__global__ __launch_bounds__(256) void proj_kernel(const float* __restrict__ X,
                                                   const float* __restrict__ Mem,
                                                   const u16* __restrict__ Wt,
                                                   const float2* __restrict__ tabQ,
                                                   const float2* __restrict__ tabK,
                                                   u16* __restrict__ Qo,
                                                   u16* __restrict__ Ko,
                                                   u16* __restrict__ Vt) {
    __shared__ u16 V_lds[128][72];   // [h][s_local], padded
    const int which = blockIdx.y;
    const int tid  = threadIdx.x;
    const int wave = tid >> 6, lane = tid & 63;
    const int l15  = lane & 15, quad = lane >> 4;
    const int rt   = blockIdx.x * 64;

    const float* src  = (which == 0) ? X : Mem;
    const u16*   Wsel = Wt + which * 65536;
    const int row_g = rt + wave * 16 + l15;            // A-frag row: m = lane&15
    const float* arow = src + (size_t)row_g * HID;

    f32x4 acc[8];
#pragma unroll
    for (int ct = 0; ct < 8; ++ct) acc[ct] = (f32x4){0.f, 0.f, 0.f, 0.f};

    for (int kc = 0; kc < 16; ++kc) {
        const float4* ap = reinterpret_cast<const float4*>(arow + kc * 32 + quad * 8);
        float4 f0 = ap[0], f1 = ap[1];
        bf16x8 a;
        a[0] = (short)f2bf(f0.x); a[1] = (short)f2bf(f0.y);
        a[2] = (short)f2bf(f0.z); a[3] = (short)f2bf(f0.w);
        a[4] = (short)f2bf(f1.x); a[5] = (short)f2bf(f1.y);
        a[6] = (short)f2bf(f1.z); a[7] = (short)f2bf(f1.w);
#pragma unroll
        for (int ct = 0; ct < 8; ++ct) {
            const bf16x8* bp = reinterpret_cast<const bf16x8*>(
                Wsel + (ct * 16 + l15) * 512 + kc * 32 + quad * 8);
            acc[ct] = __builtin_amdgcn_mfma_f32_16x16x32_bf16(a, *bp, acc[ct], 0, 0, 0);
        }
    }

    if (which <= 1) {
        // xpos epilogue in fp32, then bf16 store (row-major [t][j])
        const float2* tab = (which == 0) ? tabQ : tabK;
        u16* outp = (which == 0) ? Qo : Ko;
#pragma unroll
        for (int ct = 0; ct < 8; ++ct) {
            int j = ct * 16 + l15;
            int i = j >> 1;
            float sgn = (j & 1) ? 1.0f : -1.0f;   // rot[2i]=-x[2i+1], rot[2i+1]=+x[2i]
#pragma unroll
            for (int r = 0; r < 4; ++r) {
                int row = wave * 16 + quad * 4 + r;   // C/D: row=(lane>>4)*4+reg
                int t = rt + row;
                int n = t & 4095;
                float2 cs = tab[n * 64 + i];
                float v = acc[ct][r];
                float partner = __shfl_xor(v, 1, 64);
                float ov = v * cs.x + sgn * partner * cs.y;
                outp[(size_t)t * HD + j] = f2bf(ov);
            }
        }
    } else {
        // V: transpose via LDS -> Vt[b][h][s] bf16
#pragma unroll
        for (int ct = 0; ct < 8; ++ct) {
            int col = ct * 16 + l15;
#pragma unroll
            for (int r = 0; r < 4; ++r) {
                int row = wave * 16 + quad * 4 + r;
                V_lds[col][row] = f2bf(acc[ct][r]);
            }
        }
        __syncthreads();
        int b = rt >> 12, sb = rt & 4095;
        int h = tid >> 1, s0 = (tid & 1) * 32;
#pragma unroll
        for (int p = 0; p < 4; ++p) {
            bf16x8 v = *reinterpret_cast<const bf16x8*>(&V_lds[h][s0 + p * 8]);
            *reinterpret_cast<bf16x8*>(
                Vt + ((size_t)(b * 128 + h) * S_LEN) + sb + s0 + p * 8) = v;
        }
    }
}

// ---------------- windowed retention: flash-style, W=512 ----------------
__global__ __launch_bounds__(256) void ret_kernel(const u16* __restrict__ Qb,
                                                  const u16* __restrict__ Kb,
                                                  const u16* __restrict__ Vt,
                                                  float* __restrict__ out) {
    __shared__ u16 P_lds[4][16][72];   // per-wave 16x64 P strip, padded
    const int tid  = threadIdx.x;
    const int wave = tid >> 6, lane = tid & 63;
    const int l15  = lane & 15, quad = lane >> 4;
    const int b  = blockIdx.x >> 6;
    const int qt = (blockIdx.x & 63) * 64;
    const int qw = qt + wave * 16;

    // Q A-fragments for this wave's 16 rows, kept in registers across KV loop
    const size_t tq = (size_t)(b * 4096 + qw + l15);
    bf16x8 qfrag[4];
#pragma unroll
    for (int kc = 0; kc < 4; ++kc)
        qfrag[kc] = *reinterpret_cast<const bf16x8*>(Qb + tq * 128 + kc * 32 + quad * 8);

    f32x4 acco[8];
#pragma unroll
    for (int ht = 0; ht < 8; ++ht) acco[ht] = (f32x4){0.f, 0.f, 0.f, 0.f};

    int kv_lo = qt - WIN; if (kv_lo < 0) kv_lo = 0;
    int kv_hi = qt + 64;

    for (int kv0 = kv_lo; kv0 < kv_hi; kv0 += 64) {
        // ---- S = Q K^T (16x64 per wave) ----
        f32x4 accs[4];
#pragma unroll
        for (int ct = 0; ct < 4; ++ct) accs[ct] = (f32x4){0.f, 0.f, 0.f, 0.f};
#pragma unroll
        for (int ct = 0; ct < 4; ++ct) {
            const u16* kbase = Kb + (size_t)(b * 4096 + kv0 + ct * 16 + l15) * 128 + quad * 8;
#pragma unroll
            for (int kc = 0; kc < 4; ++kc) {
                bf16x8 kf = *reinterpret_cast<const bf16x8*>(kbase + kc * 32);
                accs[ct] = __builtin_amdgcn_mfma_f32_16x16x32_bf16(qfrag[kc], kf, accs[ct], 0, 0, 0);
            }
        }
        // ---- decay + mask, write P strip to LDS (C-layout -> row-major) ----
#pragma unroll
        for (int ct = 0; ct < 4; ++ct) {
            int kvi = kv0 + ct * 16 + l15;
#pragma unroll
            for (int r = 0; r < 4; ++r) {
                int qi = qw + quad * 4 + r;
                int d = qi - kvi;
                float val = (d >= 0) ? accs[ct][r] * exp2f((float)d * LOG2_GAMMA) : 0.0f;
                P_lds[wave][quad * 4 + r][ct * 16 + l15] = f2bf(val);
            }
        }
        __syncthreads();   // all waves same trip count; ensures LDS writes drained
        // ---- P as A-fragments ----
        bf16x8 pa0 = *reinterpret_cast<const bf16x8*>(&P_lds[wave][l15][quad * 8]);
        bf16x8 pa1 = *reinterpret_cast<const bf16x8*>(&P_lds[wave][l15][32 + quad * 8]);
        // ---- O += P V ----
#pragma unroll
        for (int ht = 0; ht < 8; ++ht) {
            const u16* vbase = Vt + (size_t)(b * 128 + ht * 16 + l15) * 4096 + kv0 + quad * 8;
            bf16x8 v0 = *reinterpret_cast<const bf16x8*>(vbase);
            bf16x8 v1 = *reinterpret_cast<const bf16x8*>(vbase + 32);
            acco[ht] = __builtin_amdgcn_mfma_f32_16x16x32_bf16(pa0, v0, acco[ht], 0, 0, 0);
            acco[ht] = __builtin_amdgcn_mfma_f32_16x16x32_bf16(pa1, v1, acco[ht], 0, 0, 0);
        }
        __syncthreads();
    }

    // ---- store O (fp32) ----
#pragma unroll
    for (int ht = 0; ht < 8; ++ht) {
#pragma unroll
        for (int r = 0; r < 4; ++r) {
            int t = b * 4096 + qw + quad * 4 + r;
            out[(size_t)t * 128 + ht * 16 + l15] = acco[ht][r];
        }
    }
}

extern "C" void kernel_launch(void* const* d_in, const int* in_sizes, int n_in,
                              void* d_out, int out_size, void* d_ws, size_t ws_size,
                              hipStream_t stream) {
    const float* X   = (const float*)d_in[0];
    const float* Mem = (const float*)d_in[1];
    const float* WQ  = (const float*)d_in[2];
    const float* WK  = (const float*)d_in[3];
    const float* WV  = (const float*)d_in[4];
    float* out = (float*)d_out;

    char* ws = (char*)d_ws;
    u16*    Qb   = (u16*)(ws);                         // 4 MB  bf16 [16384][128]
    u16*    Kb   = (u16*)(ws + ((size_t)4 << 20));     // 4 MB
    u16*    Vt   = (u16*)(ws + ((size_t)8 << 20));     // 4 MB  bf16 [4][128][4096]
    u16*    Wt   = (u16*)(ws + ((size_t)12 << 20));    // 384 KB bf16 [3][128][512]
    float2* tabQ = (float2*)(ws + ((size_t)13 << 20)); // 2 MB
    float2* tabK = (float2*)(ws + ((size_t)15 << 20)); // 2 MB  (ends at 17 MB)

    xpos_table_kernel<<<dim3(1024), dim3(256), 0, stream>>>(tabQ, tabK);
    wt_kernel<<<dim3(768), dim3(256), 0, stream>>>(WQ, WK, WV, Wt);
    proj_kernel<<<dim3(256, 3), dim3(256), 0, stream>>>(X, Mem, Wt, tabQ, tabK, Qb, Kb, Vt);
    ret_kernel<<<dim3(256), dim3(256), 0, stream>>>(Qb, Kb, Vt, out);
}

// Round 2
// 188.894 us; speedup vs baseline: 1.1419x; 1.1419x over previous
//
#include <hip/hip_runtime.h>

#define S_LEN 4096
#define HID   512
#define HD    128
#define WIN   512
#define LOG2_GAMMA (-0.0458036933f)   // log2(0.96875)

typedef short bf16x8 __attribute__((ext_vector_type(8)));
typedef float f32x4  __attribute__((ext_vector_type(4)));
typedef unsigned short u16;

static __device__ __forceinline__ u16 f2bf(float f) {
    union { float f; unsigned u; } v; v.f = f;
    unsigned r = (v.u + 0x7fffu + ((v.u >> 16) & 1u)) >> 16;  // RNE
    return (u16)r;
}

static __device__ __forceinline__ bf16x8 cvt8(float4 a, float4 b) {
    bf16x8 r;
    r[0] = (short)f2bf(a.x); r[1] = (short)f2bf(a.y);
    r[2] = (short)f2bf(a.z); r[3] = (short)f2bf(a.w);
    r[4] = (short)f2bf(b.x); r[5] = (short)f2bf(b.y);
    r[6] = (short)f2bf(b.z); r[7] = (short)f2bf(b.w);
    return r;
}

// ---------------- xpos tables: tab[n*64+i] = (cos*scale, sin*scale) ----------------
__global__ __launch_bounds__(256) void xpos_table_kernel(float2* __restrict__ tabQ,
                                                         float2* __restrict__ tabK) {
    int idx = blockIdx.x * 256 + threadIdx.x;      // 4096*64 items
    int n = idx >> 6, i = idx & 63;
    float base  = (2.0f * i + 51.2f) * (1.0f / 179.2f);       // (2i+0.4d)/(1.4d), d=128
    float power = (float)n * (1.0f / 512.0f);
    float scale = exp2f(power * log2f(base));
    float inv_freq = exp2f(-(float)i * (13.287712379549449f / 64.0f)); // 10000^(-i/64)
    float theta = (float)n * inv_freq;
    float s, c;
    sincosf(theta, &s, &c);
    tabQ[idx] = make_float2(c * scale, s * scale);
    float is = 1.0f / scale;
    tabK[idx] = make_float2(c * is, s * is);
}

// ---------------- weight transpose -> bf16, Wt[w][col][k] ----------------
__global__ __launch_bounds__(256) void wt_kernel(const float* __restrict__ WQ,
                                                 const float* __restrict__ WK,
                                                 const float* __restrict__ WV,
                                                 u16* __restrict__ Wt) {
    int idx = blockIdx.x * 256 + threadIdx.x;      // 3*128*512
    int w = idx >> 16;
    int rem = idx & 65535;
    int c = rem >> 9, k = rem & 511;
    const float* src = (w == 0) ? WQ : (w == 1) ? WK : WV;
    Wt[idx] = f2bf(src[k * HD + c]);
}

// ---------------- projections v2: weights in registers, barrier-free K-loop ----------
// grid = (256, 3); block 256. Each block: 64 tokens x 128 cols, K=512.
// Wave owns 32 cols (2 col-tiles) and all 4 row-tiles (8 acc frags).
// grid.y: 0 = Q (X, xpos up), 1 = K (Mem, xpos down), 2 = V (Mem, transpose store)
__global__ __launch_bounds__(256, 2) void proj_kernel(const float* __restrict__ X,
                                                      const float* __restrict__ Mem,
                                                      const u16* __restrict__ Wt,
                                                      const float2* __restrict__ tabQ,
                                                      const float2* __restrict__ tabK,
                                                      u16* __restrict__ Qo,
                                                      u16* __restrict__ Ko,
                                                      u16* __restrict__ Vt) {
    __shared__ u16 V_lds[128][72];   // [col][row], padded; used only by V slice
    const int which = blockIdx.y;
    const int tid  = threadIdx.x;
    const int wave = tid >> 6, lane = tid & 63;
    const int l15  = lane & 15, quad = lane >> 4;
    const int rt_base = blockIdx.x * 64;

    const u16* Wsel = Wt + which * 65536;
    const float* src = (which == 0) ? X : Mem;

    const float* arow[4];
#pragma unroll
    for (int rt = 0; rt < 4; ++rt)
        arow[rt] = src + (size_t)(rt_base + rt * 16 + l15) * HID + quad * 8;

    f32x4 acc[4][2];
#pragma unroll
    for (int rt = 0; rt < 4; ++rt) {
        acc[rt][0] = (f32x4){0.f, 0.f, 0.f, 0.f};
        acc[rt][1] = (f32x4){0.f, 0.f, 0.f, 0.f};
    }

    // prime activation double-buffer with kc=0
    float4 abuf[4][2];
#pragma unroll
    for (int rt = 0; rt < 4; ++rt) {
        abuf[rt][0] = *reinterpret_cast<const float4*>(arow[rt]);
        abuf[rt][1] = *reinterpret_cast<const float4*>(arow[rt] + 4);
    }

    for (int kh = 0; kh < 2; ++kh) {
        // preload this K-half's weight B-frags into registers (L2-hot)
        bf16x8 wfrag[2][8];
#pragma unroll
        for (int c2 = 0; c2 < 2; ++c2) {
            const u16* wp = Wsel + (wave * 32 + c2 * 16 + l15) * 512 + kh * 256 + quad * 8;
#pragma unroll
            for (int k8 = 0; k8 < 8; ++k8)
                wfrag[c2][k8] = *reinterpret_cast<const bf16x8*>(wp + k8 * 32);
        }
#pragma unroll
        for (int k8 = 0; k8 < 8; ++k8) {
            const int kc = kh * 8 + k8;   // 0..15 global k-chunk
            float4 anext[4][2];
            const bool pf = (kc < 15);
            if (pf) {
#pragma unroll
                for (int rt = 0; rt < 4; ++rt) {
                    anext[rt][0] = *reinterpret_cast<const float4*>(arow[rt] + (kc + 1) * 32);
                    anext[rt][1] = *reinterpret_cast<const float4*>(arow[rt] + (kc + 1) * 32 + 4);
                }
            }
#pragma unroll
            for (int rt = 0; rt < 4; ++rt) {
                bf16x8 a = cvt8(abuf[rt][0], abuf[rt][1]);
                acc[rt][0] = __builtin_amdgcn_mfma_f32_16x16x32_bf16(a, wfrag[0][k8], acc[rt][0], 0, 0, 0);
                acc[rt][1] = __builtin_amdgcn_mfma_f32_16x16x32_bf16(a, wfrag[1][k8], acc[rt][1], 0, 0, 0);
            }
            if (pf) {
#pragma unroll
                for (int rt = 0; rt < 4; ++rt) {
                    abuf[rt][0] = anext[rt][0];
                    abuf[rt][1] = anext[rt][1];
                }
            }
        }
    }

    if (which <= 1) {
        const float2* tab = (which == 0) ? tabQ : tabK;
        u16* outp = (which == 0) ? Qo : Ko;
#pragma unroll
        for (int c2 = 0; c2 < 2; ++c2) {
            int j = wave * 32 + c2 * 16 + l15;
            int i = j >> 1;
            float sgn = (j & 1) ? 1.0f : -1.0f;   // rot[2i]=-x[2i+1], rot[2i+1]=+x[2i]
#pragma unroll
            for (int rt = 0; rt < 4; ++rt) {
#pragma unroll
                for (int r = 0; r < 4; ++r) {
                    int t = rt_base + rt * 16 + quad * 4 + r;
                    int n = t & 4095;
                    float2 cs = tab[n * 64 + i];
                    float v = acc[rt][c2][r];
                    float partner = __shfl_xor(v, 1, 64);
                    outp[(size_t)t * HD + j] = f2bf(v * cs.x + sgn * partner * cs.y);
                }
            }
        }
    } else {
        // V: transpose via LDS -> Vt[b][h][s] bf16
#pragma unroll
        for (int c2 = 0; c2 < 2; ++c2) {
            int col = wave * 32 + c2 * 16 + l15;
#pragma unroll
            for (int rt = 0; rt < 4; ++rt)
#pragma unroll
                for (int r = 0; r < 4; ++r)
                    V_lds[col][rt * 16 + quad * 4 + r] = f2bf(acc[rt][c2][r]);
        }
        __syncthreads();
        int b = rt_base >> 12, sb = rt_base & 4095;
        int h = tid >> 1, s0 = (tid & 1) * 32;
#pragma unroll
        for (int p = 0; p < 4; ++p) {
            bf16x8 v = *reinterpret_cast<const bf16x8*>(&V_lds[h][s0 + p * 8]);
            *reinterpret_cast<bf16x8*>(
                Vt + ((size_t)(b * 128 + h) * S_LEN) + sb + s0 + p * 8) = v;
        }
    }
}

// ---------------- windowed retention v2: 32 q-rows/block, 8 waves, dbuf P ----------
// grid = 512 (b*128 + qtile), block 512. wave: rt = w&1 (q row-tile), part = w>>1 (0..3).
// QK: wave computes S[rt][cols part*16..+16]. PV: wave computes heads part*2..+2.
__global__ __launch_bounds__(512) void ret_kernel(const u16* __restrict__ Qb,
                                                  const u16* __restrict__ Kb,
                                                  const u16* __restrict__ Vt,
                                                  float* __restrict__ out) {
    __shared__ u16 P_lds[2][32][72];   // double-buffered P strip [qrow][kv], padded
    const int tid  = threadIdx.x;
    const int wave = tid >> 6, lane = tid & 63;
    const int l15  = lane & 15, quad = lane >> 4;
    const int rt   = wave & 1;         // q row-tile within block
    const int part = wave >> 1;        // 0..3
    const int b  = blockIdx.x >> 7;
    const int qt = (blockIdx.x & 127) * 32;
    const int qw = qt + rt * 16;

    // Q A-fragments for this wave's 16 q-rows
    const size_t tq = (size_t)(b * 4096 + qw + l15);
    bf16x8 qfrag[4];
#pragma unroll
    for (int kc = 0; kc < 4; ++kc)
        qfrag[kc] = *reinterpret_cast<const bf16x8*>(Qb + tq * 128 + kc * 32 + quad * 8);

    f32x4 acco[2];
    acco[0] = (f32x4){0.f, 0.f, 0.f, 0.f};
    acco[1] = (f32x4){0.f, 0.f, 0.f, 0.f};

    int kv_lo = qt - WIN; if (kv_lo < 0) kv_lo = 0;
    const int kv_hi = qt + 32;

    int p = 0;
    for (int kv0 = kv_lo; kv0 < kv_hi; kv0 += 64, p ^= 1) {
        // ---- S = Q K^T : this wave's 16x16 tile at cols part*16 ----
        f32x4 s = (f32x4){0.f, 0.f, 0.f, 0.f};
        const u16* kbase = Kb + (size_t)(b * 4096 + kv0 + part * 16 + l15) * 128 + quad * 8;
#pragma unroll
        for (int kc = 0; kc < 4; ++kc) {
            bf16x8 kf = *reinterpret_cast<const bf16x8*>(kbase + kc * 32);
            s = __builtin_amdgcn_mfma_f32_16x16x32_bf16(qfrag[kc], kf, s, 0, 0, 0);
        }
        // ---- decay + causal mask, write P strip (C-layout -> row-major) ----
        int kvi = kv0 + part * 16 + l15;
#pragma unroll
        for (int r = 0; r < 4; ++r) {
            int qi = qw + quad * 4 + r;
            int d = qi - kvi;
            float val = (d >= 0) ? s[r] * exp2f((float)d * LOG2_GAMMA) : 0.0f;
            P_lds[p][rt * 16 + quad * 4 + r][part * 16 + l15] = f2bf(val);
        }
        __syncthreads();   // only barrier per tile (P double-buffered)
        // ---- P as A-fragments for this wave's row-tile ----
        bf16x8 pa0 = *reinterpret_cast<const bf16x8*>(&P_lds[p][rt * 16 + l15][quad * 8]);
        bf16x8 pa1 = *reinterpret_cast<const bf16x8*>(&P_lds[p][rt * 16 + l15][32 + quad * 8]);
        // ---- O += P V for heads part*2, part*2+1 ----
#pragma unroll
        for (int h2 = 0; h2 < 2; ++h2) {
            int ht = part * 2 + h2;
            const u16* vbase = Vt + (size_t)(b * 128 + ht * 16 + l15) * 4096 + kv0 + quad * 8;
            bf16x8 v0 = *reinterpret_cast<const bf16x8*>(vbase);
            bf16x8 v1 = *reinterpret_cast<const bf16x8*>(vbase + 32);
            acco[h2] = __builtin_amdgcn_mfma_f32_16x16x32_bf16(pa0, v0, acco[h2], 0, 0, 0);
            acco[h2] = __builtin_amdgcn_mfma_f32_16x16x32_bf16(pa1, v1, acco[h2], 0, 0, 0);
        }
    }

    // ---- store O (fp32) ----
#pragma unroll
    for (int h2 = 0; h2 < 2; ++h2) {
        int j = (part * 2 + h2) * 16 + l15;
#pragma unroll
        for (int r = 0; r < 4; ++r) {
            int t = b * 4096 + qw + quad * 4 + r;
            out[(size_t)t * 128 + j] = acco[h2][r];
        }
    }
}

extern "C" void kernel_launch(void* const* d_in, const int* in_sizes, int n_in,
                              void* d_out, int out_size, void* d_ws, size_t ws_size,
                              hipStream_t stream) {
    const float* X   = (const float*)d_in[0];
    const float* Mem = (const float*)d_in[1];
    const float* WQ  = (const float*)d_in[2];
    const float* WK  = (const float*)d_in[3];
    const float* WV  = (const float*)d_in[4];
    float* out = (float*)d_out;

    char* ws = (char*)d_ws;
    u16*    Qb   = (u16*)(ws);                         // 4 MB  bf16 [16384][128]
    u16*    Kb   = (u16*)(ws + ((size_t)4 << 20));     // 4 MB
    u16*    Vt   = (u16*)(ws + ((size_t)8 << 20));     // 4 MB  bf16 [4][128][4096]
    u16*    Wt   = (u16*)(ws + ((size_t)12 << 20));    // 384 KB bf16 [3][128][512]
    float2* tabQ = (float2*)(ws + ((size_t)13 << 20)); // 2 MB
    float2* tabK = (float2*)(ws + ((size_t)15 << 20)); // 2 MB  (ends at 17 MB)

    xpos_table_kernel<<<dim3(1024), dim3(256), 0, stream>>>(tabQ, tabK);
    wt_kernel<<<dim3(768), dim3(256), 0, stream>>>(WQ, WK, WV, Wt);
    proj_kernel<<<dim3(256, 3), dim3(256), 0, stream>>>(X, Mem, Wt, tabQ, tabK, Qb, Kb, Vt);
    ret_kernel<<<dim3(512), dim3(512), 0, stream>>>(Qb, Kb, Vt, out);
}

// Round 3
// 145.114 us; speedup vs baseline: 1.4865x; 1.3017x over previous
//
#include <hip/hip_runtime.h>
#include <hip/hip_bf16.h>

#define S_LEN 4096
#define HID   512
#define HD    128
#define LOG2_GAMMA (-0.0458036933f)   // log2(0.96875)

typedef short bf16x8 __attribute__((ext_vector_type(8)));
typedef float f32x4  __attribute__((ext_vector_type(4)));
typedef unsigned short u16;

static __device__ __forceinline__ u16 f2bf(float f) {
    union { float f; unsigned u; } v; v.f = f;
    unsigned r = (v.u + 0x7fffu + ((v.u >> 16) & 1u)) >> 16;  // RNE
    return (u16)r;
}

static __device__ __forceinline__ unsigned pk2(float lo, float hi) {
    __hip_bfloat162 h = __float22bfloat162_rn(make_float2(lo, hi));
    union { __hip_bfloat162 h; unsigned u; } c; c.h = h; return c.u;
}
static __device__ __forceinline__ bf16x8 pack8(float4 a, float4 b) {
    union { unsigned u[4]; bf16x8 v; } r;
    r.u[0] = pk2(a.x, a.y); r.u[1] = pk2(a.z, a.w);
    r.u[2] = pk2(b.x, b.y); r.u[3] = pk2(b.z, b.w);
    return r.v;
}

// async global->LDS, 16B per lane; LDS dest = wave-uniform base + lane*16
static __device__ __forceinline__ void gload16(const void* g, void* l) {
    __builtin_amdgcn_global_load_lds(
        (const __attribute__((address_space(1))) unsigned*)g,
        (__attribute__((address_space(3))) unsigned*)l, 16, 0, 0);
}

// ---------------- xpos tables: tab[n*64+i] = (cos*scale, sin*scale) ----------------
__global__ __launch_bounds__(256) void xpos_table_kernel(float2* __restrict__ tabQ,
                                                         float2* __restrict__ tabK) {
    int idx = blockIdx.x * 256 + threadIdx.x;      // 4096*64 items
    int n = idx >> 6, i = idx & 63;
    float base  = (2.0f * i + 51.2f) * (1.0f / 179.2f);       // (2i+0.4d)/(1.4d), d=128
    float power = (float)n * (1.0f / 512.0f);
    float scale = exp2f(power * log2f(base));
    float inv_freq = exp2f(-(float)i * (13.287712379549449f / 64.0f)); // 10000^(-i/64)
    float theta = (float)n * inv_freq;
    float s, c;
    sincosf(theta, &s, &c);
    tabQ[idx] = make_float2(c * scale, s * scale);
    float is = 1.0f / scale;
    tabK[idx] = make_float2(c * is, s * is);
}

// ---------------- weight transpose -> bf16, Wt[w][col][k] ----------------
__global__ __launch_bounds__(256) void wt_kernel(const float* __restrict__ WQ,
                                                 const float* __restrict__ WK,
                                                 const float* __restrict__ WV,
                                                 u16* __restrict__ Wt) {
    int idx = blockIdx.x * 256 + threadIdx.x;      // 3*128*512
    int w = idx >> 16;
    int rem = idx & 65535;
    int c = rem >> 9, k = rem & 511;
    const float* src = (w == 0) ? WQ : (w == 1) ? WK : WV;
    Wt[idx] = f2bf(src[k * HD + c]);
}

// ---------------- projections v3: global_load_lds dbuf + XOR-swizzled LDS ----------
// grid (256, 3); block 256 (4 waves). Tile 64 tokens x 128 cols, BK=64, 8 chunks.
// Wave owns 16-row tile (rt=wave), all 8 col-tiles. Swizzle: 16B unit s of row r
// lives at LDS slot r*NU + (s ^ (r & (NU-1))) -> ds_read_b128 is 2-way (free).
__global__ __launch_bounds__(256) void proj_kernel(const float* __restrict__ X,
                                                   const float* __restrict__ Mem,
                                                   const u16* __restrict__ Wt,
                                                   const float2* __restrict__ tabQ,
                                                   const float2* __restrict__ tabK,
                                                   u16* __restrict__ Qo,
                                                   u16* __restrict__ Ko,
                                                   u16* __restrict__ Vt) {
    __shared__ __align__(16) float A_lds[2][4096];   // 2 x 16KB: 64 rows x 64 k (fp32)
    __shared__ __align__(16) u16   B_lds[2][8192];   // 2 x 16KB: 128 cols x 64 k (bf16)
    const int which = blockIdx.y;
    const int tid  = threadIdx.x;
    const int wave = tid >> 6, lane = tid & 63;
    const int l15  = lane & 15, quad = lane >> 4;
    const int rt_base = blockIdx.x * 64;
    const float* src = (which == 0) ? X : Mem;
    const u16*  Wsel = Wt + which * 65536;

    auto stage = [&](int ch, int p) {
        const int kc0 = ch * 64;
#pragma unroll
        for (int i = 0; i < 4; ++i) {              // A: 64x64 fp32, 16 units/row
            int u = i * 256 + tid;
            int row = u >> 4;
            int s = (u & 15) ^ (row & 15);
            gload16(src + (size_t)(rt_base + row) * HID + kc0 + s * 4,
                    &A_lds[p][(i * 256 + wave * 64) * 4]);
        }
#pragma unroll
        for (int i = 0; i < 4; ++i) {              // B: 128x64 bf16, 8 units/col
            int u = i * 256 + tid;
            int col = u >> 3;
            int s = (u & 7) ^ (col & 7);
            gload16(Wsel + (size_t)col * HID + kc0 + s * 8,
                    &B_lds[p][(i * 256 + wave * 64) * 8]);
        }
    };

    f32x4 acc[8];
#pragma unroll
    for (int ct = 0; ct < 8; ++ct) acc[ct] = (f32x4){0.f, 0.f, 0.f, 0.f};

    stage(0, 0);
    for (int ch = 0; ch < 8; ++ch) {
        const int p = ch & 1;
        __syncthreads();                            // buf p ready; buf p^1 free
        if (ch < 7) stage(ch + 1, p ^ 1);
#pragma unroll
        for (int kc2 = 0; kc2 < 2; ++kc2) {
            const int s0 = kc2 * 8 + quad * 2;      // A unit index (4 floats/unit)
            const int arow = wave * 16 + l15;       // A-frag row m = lane&15
            float4 af0 = *(const float4*)&A_lds[p][(arow * 16 + ((s0    ) ^ l15)) * 4];
            float4 af1 = *(const float4*)&A_lds[p][(arow * 16 + ((s0 + 1) ^ l15)) * 4];
            bf16x8 a = pack8(af0, af1);
#pragma unroll
            for (int ct = 0; ct < 8; ++ct) {
                const int col = ct * 16 + l15;
                const int sb = (kc2 * 4 + quad) ^ (col & 7);
                bf16x8 bf = *(const bf16x8*)&B_lds[p][(col * 8 + sb) * 8];
                acc[ct] = __builtin_amdgcn_mfma_f32_16x16x32_bf16(a, bf, acc[ct], 0, 0, 0);
            }
        }
    }

    if (which <= 1) {
        const float2* tab = (which == 0) ? tabQ : tabK;
        u16* outp = (which == 0) ? Qo : Ko;
#pragma unroll
        for (int ct = 0; ct < 8; ++ct) {
            int j = ct * 16 + l15;
            int i = j >> 1;
            float sgn = (j & 1) ? 1.0f : -1.0f;     // rot[2i]=-x[2i+1], rot[2i+1]=+x[2i]
#pragma unroll
            for (int r = 0; r < 4; ++r) {
                int t = rt_base + wave * 16 + quad * 4 + r;
                int n = t & 4095;
                float2 cs = tab[n * 64 + i];
                float v = acc[ct][r];
                float partner = __shfl_xor(v, 1, 64);
                outp[(size_t)t * HD + j] = f2bf(v * cs.x + sgn * partner * cs.y);
            }
        }
    } else {
        // V: transpose via LDS scratch (reuses A_lds region) -> Vt[b][h][s]
        u16* Vs = (u16*)&A_lds[0][0];               // [128][80] u16 = 20KB < 32KB
        __syncthreads();                             // all waves done with K-loop LDS
#pragma unroll
        for (int ct = 0; ct < 8; ++ct) {
            int col = ct * 16 + l15;
#pragma unroll
            for (int r = 0; r < 4; ++r)
                Vs[col * 80 + wave * 16 + quad * 4 + r] = f2bf(acc[ct][r]);
        }
        __syncthreads();
        int b = rt_base >> 12, sb = rt_base & 4095;
        int h = tid >> 1, sof = (tid & 1) * 32;
#pragma unroll
        for (int pp = 0; pp < 4; ++pp) {
            bf16x8 v = *(const bf16x8*)&Vs[h * 80 + sof + pp * 8];
            *(bf16x8*)(Vt + (size_t)(b * 128 + h) * S_LEN + sb + sof + pp * 8) = v;
        }
    }
}

// ---------------- windowed retention v3: wave-private P (no P barrier) -------------
// grid 256 (b*64 + qtile64); block 256 (4 waves, wave owns 16 q-rows).
// K tile staged via swizzled global_load_lds (dbuf, 1 barrier/tile); V direct regs.
__global__ __launch_bounds__(256) void ret_kernel(const u16* __restrict__ Qb,
                                                  const u16* __restrict__ Kb,
                                                  const u16* __restrict__ Vt,
                                                  float* __restrict__ out) {
    __shared__ __align__(16) u16   K_lds[2][8192];      // 2 x 16KB: 64 kv x 128 hd
    __shared__ __align__(16) float P_lds[4][16][68];    // per-wave 16x64 fp32 strip
    const int tid  = threadIdx.x;
    const int wave = tid >> 6, lane = tid & 63;
    const int l15  = lane & 15, quad = lane >> 4;
    const int b  = blockIdx.x >> 6;
    const int qt = (blockIdx.x & 63) * 64;
    const int qw = qt + wave * 16;

    auto stageK = [&](int kv0, int p) {
#pragma unroll
        for (int i = 0; i < 4; ++i) {
            int u = i * 256 + tid;
            int kvr = u >> 4;
            int s = (u & 15) ^ (kvr & 15);
            gload16(Kb + (size_t)(b * S_LEN + kv0 + kvr) * HD + s * 8,
                    &K_lds[p][(i * 256 + wave * 64) * 8]);
        }
    };

    // Q A-fragments, register-resident across KV loop
    const size_t tq = (size_t)(b * S_LEN + qw + l15);
    bf16x8 qfrag[4];
#pragma unroll
    for (int kc = 0; kc < 4; ++kc)
        qfrag[kc] = *(const bf16x8*)(Qb + tq * HD + kc * 32 + quad * 8);

    f32x4 acco[8];
#pragma unroll
    for (int ht = 0; ht < 8; ++ht) acco[ht] = (f32x4){0.f, 0.f, 0.f, 0.f};

    int kv_lo = qt - 448; if (kv_lo < 0) kv_lo = 0;   // covers all decay d<=448 (γ^449≈6e-7)
    const int nt = (qt + 64 - kv_lo) >> 6;

    stageK(kv_lo, 0);
    for (int it = 0; it < nt; ++it) {
        const int p = it & 1;
        const int kv0 = kv_lo + it * 64;
        __syncthreads();                               // K buf p ready; p^1 free
        if (it + 1 < nt) stageK(kv0 + 64, p ^ 1);

        // V prefetch into registers (consumed at tile end -> latency hidden)
        bf16x8 vf[8][2];
#pragma unroll
        for (int ht = 0; ht < 8; ++ht) {
            const u16* vb = Vt + (size_t)(b * HD + ht * 16 + l15) * S_LEN + kv0 + quad * 8;
            vf[ht][0] = *(const bf16x8*)vb;
            vf[ht][1] = *(const bf16x8*)(vb + 32);
        }

        // ---- S = Q K^T (16x64 per wave) from swizzled K_lds ----
        f32x4 accs[4];
#pragma unroll
        for (int ct = 0; ct < 4; ++ct) accs[ct] = (f32x4){0.f, 0.f, 0.f, 0.f};
#pragma unroll
        for (int ct = 0; ct < 4; ++ct) {
            const int kvr = ct * 16 + l15;
#pragma unroll
            for (int kc = 0; kc < 4; ++kc) {
                bf16x8 kf = *(const bf16x8*)
                    &K_lds[p][(kvr * 16 + ((kc * 4 + quad) ^ (kvr & 15))) * 8];
                accs[ct] = __builtin_amdgcn_mfma_f32_16x16x32_bf16(qfrag[kc], kf, accs[ct], 0, 0, 0);
            }
        }
        // ---- decay + causal mask -> wave-private P strip (fp32, no barrier) ----
#pragma unroll
        for (int ct = 0; ct < 4; ++ct) {
            int kvi = kv0 + ct * 16 + l15;
#pragma unroll
            for (int r = 0; r < 4; ++r) {
                int d = (qw + quad * 4 + r) - kvi;
                float w = exp2f((float)d * LOG2_GAMMA);
                P_lds[wave][quad * 4 + r][ct * 16 + l15] = (d >= 0) ? accs[ct][r] * w : 0.0f;
            }
        }
        // ---- P as A-fragments (within-wave lgkmcnt only) ----
        float4 p00 = *(const float4*)&P_lds[wave][l15][quad * 8];
        float4 p01 = *(const float4*)&P_lds[wave][l15][quad * 8 + 4];
        float4 p10 = *(const float4*)&P_lds[wave][l15][32 + quad * 8];
        float4 p11 = *(const float4*)&P_lds[wave][l15][32 + quad * 8 + 4];
        bf16x8 pa0 = pack8(p00, p01);
        bf16x8 pa1 = pack8(p10, p11);
        // ---- O += P V ----
#pragma unroll
        for (int ht = 0; ht < 8; ++ht) {
            acco[ht] = __builtin_amdgcn_mfma_f32_16x16x32_bf16(pa0, vf[ht][0], acco[ht], 0, 0, 0);
            acco[ht] = __builtin_amdgcn_mfma_f32_16x16x32_bf16(pa1, vf[ht][1], acco[ht], 0, 0, 0);
        }
    }

    // ---- store O (fp32) ----
#pragma unroll
    for (int ht = 0; ht < 8; ++ht)
#pragma unroll
        for (int r = 0; r < 4; ++r)
            out[(size_t)(b * S_LEN + qw + quad * 4 + r) * HD + ht * 16 + l15] = acco[ht][r];
}

extern "C" void kernel_launch(void* const* d_in, const int* in_sizes, int n_in,
                              void* d_out, int out_size, void* d_ws, size_t ws_size,
                              hipStream_t stream) {
    const float* X   = (const float*)d_in[0];
    const float* Mem = (const float*)d_in[1];
    const float* WQ  = (const float*)d_in[2];
    const float* WK  = (const float*)d_in[3];
    const float* WV  = (const float*)d_in[4];
    float* out = (float*)d_out;

    char* ws = (char*)d_ws;
    u16*    Qb   = (u16*)(ws);                         // 4 MB  bf16 [16384][128]
    u16*    Kb   = (u16*)(ws + ((size_t)4 << 20));     // 4 MB
    u16*    Vt   = (u16*)(ws + ((size_t)8 << 20));     // 4 MB  bf16 [4][128][4096]
    u16*    Wt   = (u16*)(ws + ((size_t)12 << 20));    // 384 KB bf16 [3][128][512]
    float2* tabQ = (float2*)(ws + ((size_t)13 << 20)); // 2 MB
    float2* tabK = (float2*)(ws + ((size_t)15 << 20)); // 2 MB  (ends at 17 MB)

    xpos_table_kernel<<<dim3(1024), dim3(256), 0, stream>>>(tabQ, tabK);
    wt_kernel<<<dim3(768), dim3(256), 0, stream>>>(WQ, WK, WV, Wt);
    proj_kernel<<<dim3(256, 3), dim3(256), 0, stream>>>(X, Mem, Wt, tabQ, tabK, Qb, Kb, Vt);
    ret_kernel<<<dim3(256), dim3(256), 0, stream>>>(Qb, Kb, Vt, out);
}